// Round 8
// baseline (491.090 us; speedup 1.0000x reference)
//
#include <hip/hip_runtime.h>
#include <math.h>

#define N_ROWS 16384
#define VOCAB  8192
#define EMB    256

// ---- MFMA path tiling ----
#define BM 128
#define BV 128
#define BK 64                      // halfs per staged K-chunk (2 MFMA k-steps)
#define VSPLIT 8                   // grid (128, 8)
#define VRANGE (VOCAB / VSPLIT)    // 1024
#define NVT    (VRANGE / BV)       // 8
#define TAU 0.15f                  // rescue margin: >= 2*max|dist err| (fp16 inputs)

typedef _Float16 half8 __attribute__((ext_vector_type(8)));
typedef _Float16 half4 __attribute__((ext_vector_type(4)));
typedef float floatx4 __attribute__((ext_vector_type(4)));

// async global->LDS DMA, 16 B/lane; LDS dest = wave-uniform base + lane*16
__device__ __forceinline__ void load_lds16(const _Float16* g, _Float16* l) {
    __builtin_amdgcn_global_load_lds(
        (const __attribute__((address_space(1))) void*)g,
        (__attribute__((address_space(3))) void*)l, 16, 0, 0);
}

// ---------------------------------------------------------------------------
// PREP (1 dispatch replaces esq + split + 3 memsets):
// blocks [0,2048): cb rows 4/block — fp16 convert + esq wave-reduce + zero
//                  cnt (4/block) + init rkey (8/block) + flagcnt/done (blk 0)
// blocks [2048,6144): z fp16 convert, 1 float4/thread
// ---------------------------------------------------------------------------
__global__ void prep_kernel(const float* __restrict__ z, const float* __restrict__ cb,
                            _Float16* __restrict__ zh, _Float16* __restrict__ ch,
                            float* __restrict__ esq, float* __restrict__ cnt,
                            unsigned long long* __restrict__ rkey,
                            int* __restrict__ flagcnt, int* __restrict__ done) {
    const int b = blockIdx.x, t = threadIdx.x;
    if (b < VOCAB / 4) {
        const int row  = b * 4 + (t >> 6);
        const int lane = t & 63;
        const float4 f = *(const float4*)(cb + (size_t)row * EMB + lane * 4);
        half4 h;
        h.x = (_Float16)f.x; h.y = (_Float16)f.y; h.z = (_Float16)f.z; h.w = (_Float16)f.w;
        *(half4*)(ch + (size_t)row * EMB + lane * 4) = h;
        float s = f.x * f.x + f.y * f.y + f.z * f.z + f.w * f.w;
        #pragma unroll
        for (int off = 32; off > 0; off >>= 1) s += __shfl_down(s, off, 64);
        if (lane == 0) esq[row] = s;
        if (t < 4) cnt[b * 4 + t] = 0.0f;
        if (t >= 8 && t < 16) rkey[b * 8 + (t - 8)] = ~0ull;
        if (b == 0 && t == 4) *flagcnt = 0;
        if (b == 0 && t == 5) *done = 0;
    } else {
        const size_t idx4 = (size_t)(b - VOCAB / 4) * 256 + t;
        const float4 f = *(const float4*)(z + idx4 * 4);
        half4 h;
        h.x = (_Float16)f.x; h.y = (_Float16)f.y; h.z = (_Float16)f.z; h.w = (_Float16)f.w;
        *(half4*)(zh + idx4 * 4) = h;
    }
}

// ---------------------------------------------------------------------------
// MFMA dist kernel v8.
// acc init = -0.5*esq[col]  =>  dist = -2*acc; per-row ARGMAX of acc.
// LDS tiles [row][64 halfs] (128 B rows), XOR-swizzled chunks:
//   slot (r,c) holds global chunk (r, c ^ (r&7)).
// Staged by global_load_lds dwordx4 (source permuted per lane; dest linear).
// Reads: chunk' = (s*4+quad) ^ (lr&7) -> each quad's 16 lanes tile all 32
// banks (2-way only). 32 MFMAs per barrier pair (BK=64).
// ---------------------------------------------------------------------------
__global__ __launch_bounds__(256, 3)
void mfma_dist_kernel(const _Float16* __restrict__ zh, const _Float16* __restrict__ ch,
                      const float* __restrict__ esq,
                      float* __restrict__ pd1, int* __restrict__ pi1,
                      float* __restrict__ pd2) {
    __shared__ _Float16 zs[BM * BK];   // 16 KB
    __shared__ _Float16 cs[BV * BK];   // 16 KB
    float* sc_d1 = (float*)zs;         // end-phase alias (3 KB)
    float* sc_d2 = sc_d1 + BM * 2;
    int*   sc_i1 = (int*)(sc_d2 + BM * 2);

    const int row0  = blockIdx.x * BM;
    const int vbase = blockIdx.y * VRANGE;

    const int tid  = threadIdx.x;
    const int w    = tid >> 6;
    const int lane = tid & 63;
    const int lr   = lane & 15;
    const int quad = lane >> 4;
    const int mh   = (w >> 1) * 64;    // wave m-origin
    const int vh   = (w & 1) * 64;     // wave v-origin

    // fragment read addressing (lane-constant, zero VALU in the hot loop)
    const int q7   = quad ^ (lr & 7);
    const int offA0 = q7 * 8;                // kstep 0 chunk offset (halfs)
    const int offA1 = (4 ^ q7) * 8;          // kstep 1
    int rA[4], rB[4];
    #pragma unroll
    for (int i = 0; i < 4; ++i) { rA[i] = (mh + i * 16 + lr) * BK; rB[i] = (vh + i * 16 + lr) * BK; }

    // staging addressing: slot ss = w*256 + q*64 + lane; r=ss>>3, c=lane&7
    const int schunk = (lane & 7) ^ (lane >> 3);            // c ^ (r&7), lane-const
    const _Float16* zsrc = zh + (size_t)(row0 + w * 32 + (lane >> 3)) * EMB + schunk * 8;

    // per-lane deferred top-2 (maximize acc): 16 rows per lane
    float m1[16], m2[16]; int i1[16];
    #pragma unroll
    for (int t = 0; t < 16; ++t) { m1[t] = -INFINITY; m2[t] = -INFINITY; i1[t] = 0; }

    // esq prefetch (vt=0)
    float ev[4];
    #pragma unroll
    for (int j = 0; j < 4; ++j) ev[j] = esq[vbase + vh + j * 16 + lr];

    for (int vt = 0; vt < NVT; ++vt) {
        const int v0 = vbase + vt * BV;
        const _Float16* csrc = ch + (size_t)(v0 + w * 32 + (lane >> 3)) * EMB + schunk * 8;

        // acc init = -0.5*esq[col]  (col = vh + j*16 + lr, same for all regs)
        floatx4 acc[4][4];
        #pragma unroll
        for (int j = 0; j < 4; ++j) {
            const float e2 = -0.5f * ev[j];
            #pragma unroll
            for (int i = 0; i < 4; ++i) acc[i][j] = (floatx4)e2;
        }
        // prefetch next vt's esq (loads retire during kt loop)
        float evn[4];
        {
            const int vtn = (vt + 1 < NVT) ? vt + 1 : vt;
            #pragma unroll
            for (int j = 0; j < 4; ++j) evn[j] = esq[vbase + vtn * BV + vh + j * 16 + lr];
        }

        #pragma unroll 1
        for (int kt = 0; kt < EMB / BK; ++kt) {
            const int ko = kt * BK;
            #pragma unroll
            for (int q = 0; q < 4; ++q) {
                load_lds16(zsrc + (size_t)q * 8 * EMB + ko, &zs[w * 2048 + q * 512]);
                load_lds16(csrc + (size_t)q * 8 * EMB + ko, &cs[w * 2048 + q * 512]);
            }
            __syncthreads();

            #pragma unroll
            for (int s = 0; s < 2; ++s) {
                const int off = s ? offA1 : offA0;
                half8 a[4];
                #pragma unroll
                for (int i = 0; i < 4; ++i) a[i] = *(const half8*)&zs[rA[i] + off];
                #pragma unroll
                for (int j = 0; j < 4; ++j) {
                    const half8 b = *(const half8*)&cs[rB[j] + off];
                    #pragma unroll
                    for (int i = 0; i < 4; ++i)
                        acc[i][j] = __builtin_amdgcn_mfma_f32_16x16x32_f16(a[i], b, acc[i][j], 0, 0, 0);
                }
            }
            __syncthreads();
        }

        // epilogue: register-only top-2 (argmax acc)
        int vj[4];
        #pragma unroll
        for (int j = 0; j < 4; ++j) vj[j] = v0 + vh + j * 16 + lr;
        #pragma unroll
        for (int i = 0; i < 4; ++i) {
            #pragma unroll
            for (int reg = 0; reg < 4; ++reg) {
                const int t = i * 4 + reg;
                #pragma unroll
                for (int j = 0; j < 4; ++j) {
                    const float a = acc[i][j][reg];
                    m2[t] = fmaxf(m2[t], fminf(a, m1[t]));
                    i1[t] = (a > m1[t]) ? vj[j] : i1[t];
                    m1[t] = fmaxf(m1[t], a);
                }
            }
        }
        #pragma unroll
        for (int j = 0; j < 4; ++j) ev[j] = evn[j];
    }

    // ONE cross-lane reduce: 16 lr-lanes (same quad) share each row
    #pragma unroll
    for (int t = 0; t < 16; ++t) {
        float a1 = m1[t], a2 = m2[t]; int ii = i1[t];
        #pragma unroll
        for (int off = 1; off < 16; off <<= 1) {
            const float o1 = __shfl_xor(a1, off, 64);
            const int   oi = __shfl_xor(ii, off, 64);
            const float o2 = __shfl_xor(a2, off, 64);
            if (o1 > a1) { a2 = fmaxf(a1, o2); a1 = o1; ii = oi; }
            else         { a2 = fmaxf(a2, o1); }
        }
        m1[t] = a1; m2[t] = a2; i1[t] = ii;
    }
    // all waves past the kt-loop's trailing barrier -> alias of zs is safe
    if (lr == 0) {
        #pragma unroll
        for (int t = 0; t < 16; ++t) {
            const int r = mh + (t >> 2) * 16 + quad * 4 + (t & 3);
            sc_d1[r * 2 + (w & 1)] = m1[t];
            sc_d2[r * 2 + (w & 1)] = m2[t];
            sc_i1[r * 2 + (w & 1)] = i1[t];
        }
    }
    __syncthreads();
    if (tid < BM) {
        float a1 = sc_d1[tid * 2], a2 = sc_d2[tid * 2]; int ii = sc_i1[tid * 2];
        const float o1 = sc_d1[tid * 2 + 1], o2 = sc_d2[tid * 2 + 1];
        const int   oi = sc_i1[tid * 2 + 1];
        if (o1 > a1) { a2 = fmaxf(a1, o2); a1 = o1; ii = oi; }
        else         { a2 = fmaxf(a2, o1); }
        const size_t o = (size_t)blockIdx.y * N_ROWS + row0 + tid;
        pd1[o] = -2.0f * a1; pi1[o] = ii; pd2[o] = -2.0f * a2;
    }
}

// ---------------------------------------------------------------------------
// Combine: merge VSPLIT top-2 partials; margin >= TAU -> commit, else flag.
// ---------------------------------------------------------------------------
__global__ void combine_kernel(const float* __restrict__ pd1, const int* __restrict__ pi1,
                               const float* __restrict__ pd2,
                               const float* __restrict__ cb,
                               float* __restrict__ tokens, float* __restrict__ zq,
                               float* __restrict__ cnt,
                               int* __restrict__ flagcnt, int* __restrict__ flaglist) {
    const int wave = threadIdx.x >> 6;
    const int lane = threadIdx.x & 63;
    const int row  = blockIdx.x * 4 + wave;

    float d1 = INFINITY, d2 = INFINITY; int i1 = 0;
    #pragma unroll
    for (int s = 0; s < VSPLIT; ++s) {
        const size_t o = (size_t)s * N_ROWS + row;
        const float od1 = pd1[o], od2 = pd2[o]; const int oi1 = pi1[o];
        if (od1 < d1) { d2 = fminf(d1, od2); d1 = od1; i1 = oi1; }
        else          { d2 = fminf(d2, od1); }
    }
    if ((d2 - d1) < TAU) {
        if (lane == 0) {
            const int pos = atomicAdd(flagcnt, 1);
            flaglist[pos] = row;
        }
        return;   // rescue writes this row
    }
    if (lane == 0) {
        tokens[row] = (float)i1;
        atomicAdd(&cnt[i1], 1.0f);
    }
    const float4 v = *(const float4*)(cb + (size_t)i1 * EMB + lane * 4);
    *(float4*)(zq + (size_t)row * EMB + lane * 4) = v;
}

// ---------------------------------------------------------------------------
// Rescue (v3 + fused writer): exact fp32 argmin for flagged rows.
// Job = (row, 32-code chunk) per wave; 4 lanes/code x 16 codes parallel.
// Last-finished block (device done-counter) performs token/zq/cnt writes.
// ---------------------------------------------------------------------------
__global__ void rescue3_kernel(const int* __restrict__ flagcnt, const int* __restrict__ flaglist,
                               const float* __restrict__ z, const float* __restrict__ cb,
                               const float* __restrict__ esq,
                               unsigned long long* __restrict__ rkey,
                               int* __restrict__ done,
                               float* __restrict__ tokens, float* __restrict__ zq,
                               float* __restrict__ cnt) {
    const int tid  = threadIdx.x;
    const int w    = tid >> 6;
    const int lane = tid & 63;
    const int g    = lane >> 2;
    const int s    = lane & 3;
    const int n = *flagcnt;
    const int waveId = blockIdx.x * 4 + w;
    const int nwaves = gridDim.x * 4;
    const int njobs  = n * 256;
    for (int j = waveId; j < njobs; j += nwaves) {
        const int row = flaglist[j >> 8];
        const int c0  = (j & 255) * 32;
        const float* zr = z + (size_t)row * EMB;
        float bd = INFINITY; int bv = 0;
        #pragma unroll
        for (int gs = 0; gs < 2; ++gs) {
            const int v = c0 + gs * 16 + g;
            const float* cr = cb + (size_t)v * EMB;
            float p = 0.0f;
            #pragma unroll
            for (int k = 0; k < 16; ++k) {
                const float4 c4 = *(const float4*)(cr + k * 16 + s * 4);
                const float4 z4 = *(const float4*)(zr + k * 16 + s * 4);
                p += z4.x * c4.x + z4.y * c4.y + z4.z * c4.z + z4.w * c4.w;
            }
            p += __shfl_xor(p, 1, 64);
            p += __shfl_xor(p, 2, 64);
            const float d = esq[v] - 2.0f * p;
            if (d < bd || (d == bd && v < bv)) { bd = d; bv = v; }
        }
        #pragma unroll
        for (int off = 4; off < 64; off <<= 1) {
            const float od = __shfl_xor(bd, off, 64);
            const int   ov = __shfl_xor(bv, off, 64);
            if (od < bd || (od == bd && ov < bv)) { bd = od; bv = ov; }
        }
        if (lane == 0) {
            unsigned int u = __float_as_uint(bd);
            u = (u & 0x80000000u) ? ~u : (u | 0x80000000u);
            atomicMin(rkey + row, ((unsigned long long)u << 32) | (unsigned int)bv);
        }
    }

    // ---- last-block writer ----
    __shared__ int amlast;
    __threadfence();
    if (tid == 0) amlast = (atomicAdd(done, 1) == (int)gridDim.x - 1);
    __syncthreads();
    if (!amlast) return;
    __threadfence();
    for (int f = w; f < n; f += 4) {
        const int row = flaglist[f];
        const int v = (int)(unsigned int)(rkey[row] & 0xFFFFFFFFull);
        if (lane == 0) {
            tokens[row] = (float)v;
            atomicAdd(&cnt[v], 1.0f);
        }
        const float4 c4 = *(const float4*)(cb + (size_t)v * EMB + lane * 4);
        *(float4*)(zq + (size_t)row * EMB + lane * 4) = c4;
    }
}

// ===========================================================================
// Fallback (round-3 fp32 path) if ws is too small.
// ===========================================================================
__global__ void esq_kernel(const float* __restrict__ cb, float* __restrict__ esq) {
    const int wave = threadIdx.x >> 6;
    const int lane = threadIdx.x & 63;
    const int row  = blockIdx.x * 4 + wave;
    const float4 v = *(const float4*)(cb + (size_t)row * EMB + lane * 4);
    float s = v.x * v.x + v.y * v.y + v.z * v.z + v.w * v.w;
    #pragma unroll
    for (int off = 32; off > 0; off >>= 1) s += __shfl_down(s, off, 64);
    if (lane == 0) esq[row] = s;
}

#define FLSTR 36
__global__ __launch_bounds__(256, 2)
void fb_dist_kernel(const float* __restrict__ z, const float* __restrict__ cb,
                    const float* __restrict__ esq,
                    float* __restrict__ pdist, int* __restrict__ pidx) {
    __shared__ float zs[BM][FLSTR];
    __shared__ float es[BV][FLSTR];
    __shared__ float rdist[16][16];
    __shared__ int   ridx [16][16];
    const int row0 = blockIdx.x * BM, vbase = blockIdx.y * VRANGE;
    const int tid = threadIdx.x, wave = tid >> 6, lane = tid & 63;
    const int wly = (lane >> 3) & 7, wlx = lane & 7;
    const int wbase = (wave >> 1) * 64, cbase = (wave & 1) * 64;
    const int arow = wbase + wly, bcol = cbase + wlx;
    const int rowSlot = (wave >> 1) * 8 + wly, colSlot = (wave & 1) * 8 + wlx;
    const int sc4 = tid & 7, sr0 = tid >> 3;
    float best[8]; int bidx[8];
    #pragma unroll
    for (int i = 0; i < 8; ++i) { best[i] = INFINITY; bidx[i] = 0; }
    for (int vt = 0; vt < NVT; ++vt) {
        const int v0 = vbase + vt * BV;
        float acc[8][8];
        #pragma unroll
        for (int i = 0; i < 8; ++i)
            #pragma unroll
            for (int j = 0; j < 8; ++j) acc[i][j] = 0.0f;
        #pragma unroll 1
        for (int kt = 0; kt < EMB / 32; ++kt) {
            #pragma unroll
            for (int t = 0; t < 4; ++t) {
                const int r = sr0 + 32 * t;
                *(float4*)&zs[r][sc4 * 4] = *(const float4*)(z  + (size_t)(row0 + r) * EMB + kt * 32 + sc4 * 4);
                *(float4*)&es[r][sc4 * 4] = *(const float4*)(cb + (size_t)(v0 + r) * EMB + kt * 32 + sc4 * 4);
            }
            __syncthreads();
            #pragma unroll 1
            for (int k0 = 0; k0 < 8; ++k0) {
                const int kk = k0 * 4;
                float a[8][4];
                #pragma unroll
                for (int i = 0; i < 8; ++i) {
                    const float4 a4 = *(const float4*)&zs[arow + 8 * i][kk];
                    a[i][0] = a4.x; a[i][1] = a4.y; a[i][2] = a4.z; a[i][3] = a4.w;
                }
                #pragma unroll
                for (int j = 0; j < 8; ++j) {
                    const float4 b4 = *(const float4*)&es[bcol + 8 * j][kk];
                    #pragma unroll
                    for (int i = 0; i < 8; ++i) {
                        acc[i][j] += a[i][0] * b4.x; acc[i][j] += a[i][1] * b4.y;
                        acc[i][j] += a[i][2] * b4.z; acc[i][j] += a[i][3] * b4.w;
                    }
                }
            }
            __syncthreads();
        }
        #pragma unroll
        for (int j = 0; j < 8; ++j) {
            const int v = v0 + bcol + 8 * j;
            const float evv = esq[v];
            #pragma unroll
            for (int i = 0; i < 8; ++i) {
                const float d = evv - 2.0f * acc[i][j];
                if (d < best[i]) { best[i] = d; bidx[i] = v; }
            }
        }
    }
    for (int i = 0; i < 8; ++i) {
        rdist[rowSlot][colSlot] = best[i];
        ridx [rowSlot][colSlot] = bidx[i];
        __syncthreads();
        if (colSlot == 0) {
            float bd = rdist[rowSlot][0]; int bi = ridx[rowSlot][0];
            #pragma unroll
            for (int t = 1; t < 16; ++t) {
                const float d = rdist[rowSlot][t]; const int ii = ridx[rowSlot][t];
                if (d < bd || (d == bd && ii < bi)) { bd = d; bi = ii; }
            }
            const int row = row0 + wbase + 8 * i + wly;
            pdist[(size_t)blockIdx.y * N_ROWS + row] = bd;
            pidx [(size_t)blockIdx.y * N_ROWS + row] = bi;
        }
        __syncthreads();
    }
}

__global__ void fb_combine_kernel(const float* __restrict__ pdist, const int* __restrict__ pidx,
                                  const float* __restrict__ cb,
                                  float* __restrict__ tokens, float* __restrict__ zq,
                                  float* __restrict__ cnt) {
    const int wave = threadIdx.x >> 6, lane = threadIdx.x & 63;
    const int row = blockIdx.x * 4 + wave;
    float bd = INFINITY; int bi = 0;
    #pragma unroll
    for (int s = 0; s < VSPLIT; ++s) {
        const float d = pdist[(size_t)s * N_ROWS + row];
        const int ii  = pidx [(size_t)s * N_ROWS + row];
        if (d < bd || (d == bd && ii < bi)) { bd = d; bi = ii; }
    }
    if (lane == 0) { tokens[row] = (float)bi; atomicAdd(&cnt[bi], 1.0f); }
    const float4 v = *(const float4*)(cb + (size_t)bi * EMB + lane * 4);
    *(float4*)(zq + (size_t)row * EMB + lane * 4) = v;
}

// ---------------------------------------------------------------------------
// d_out: [0,N) tokens | [N, N+N*EMB) zq | +VOCAB ref_count
// ws: zh | ch | esq | pd1|pd2|pi1 | rkey | flagcnt+done | flaglist  ~= 13.8 MB
// 4 dispatches: prep -> mfma_dist -> combine -> rescue3(+writer)
// ---------------------------------------------------------------------------
extern "C" void kernel_launch(void* const* d_in, const int* in_sizes, int n_in,
                              void* d_out, int out_size, void* d_ws, size_t ws_size,
                              hipStream_t stream) {
    const float* z  = (const float*)d_in[0];
    const float* cb = (const float*)d_in[1];

    float* out    = (float*)d_out;
    float* tokens = out;
    float* zq     = out + N_ROWS;
    float* cnt    = out + N_ROWS + (size_t)N_ROWS * EMB;

    const size_t ZE = (size_t)N_ROWS * EMB, CE = (size_t)VOCAB * EMB, P = (size_t)VSPLIT * N_ROWS;
    const size_t NEED = (ZE + CE) * sizeof(_Float16) + VOCAB * 4
                      + 3 * P * 4 + (size_t)N_ROWS * 8 + 256 + N_ROWS * 4;

    if (ws_size >= NEED) {
        char* p = (char*)d_ws;
        _Float16* zh = (_Float16*)p;            p += ZE * 2;
        _Float16* ch = (_Float16*)p;            p += CE * 2;
        float* esq   = (float*)p;               p += VOCAB * 4;
        float* pd1   = (float*)p;               p += P * 4;
        float* pd2   = (float*)p;               p += P * 4;
        int*   pi1   = (int*)p;                 p += P * 4;
        unsigned long long* rkey = (unsigned long long*)p;  p += (size_t)N_ROWS * 8;
        int*   flagcnt = (int*)p;
        int*   done    = flagcnt + 1;           p += 256;
        int*   flaglist = (int*)p;

        prep_kernel<<<VOCAB / 4 + (int)(ZE / 4 / 256), 256, 0, stream>>>(
            z, cb, zh, ch, esq, cnt, rkey, flagcnt, done);
        mfma_dist_kernel<<<dim3(N_ROWS / BM, VSPLIT), 256, 0, stream>>>(
            zh, ch, esq, pd1, pi1, pd2);
        combine_kernel<<<N_ROWS / 4, 256, 0, stream>>>(
            pd1, pi1, pd2, cb, tokens, zq, cnt, flagcnt, flaglist);
        rescue3_kernel<<<2048, 256, 0, stream>>>(
            flagcnt, flaglist, z, cb, esq, rkey, done, tokens, zq, cnt);
    } else {
        float* esq   = (float*)d_ws;
        float* pdist = esq + VOCAB;
        int*   pidx  = (int*)(pdist + P);
        hipMemsetAsync(cnt, 0, VOCAB * sizeof(float), stream);
        esq_kernel<<<VOCAB / 4, 256, 0, stream>>>(cb, esq);
        fb_dist_kernel<<<dim3(N_ROWS / BM, VSPLIT), 256, 0, stream>>>(z, cb, esq, pdist, pidx);
        fb_combine_kernel<<<N_ROWS / 4, 256, 0, stream>>>(pdist, pidx, cb, tokens, zq, cnt);
    }
}

// Round 9
// 297.612 us; speedup vs baseline: 1.6501x; 1.6501x over previous
//
#include <hip/hip_runtime.h>
#include <math.h>

#define N_ROWS 16384
#define VOCAB  8192
#define EMB    256

// ---- MFMA path tiling ----
#define BM 128
#define BV 128
#define BK 64                      // halfs per staged K-chunk (2 MFMA k-steps)
#define VSPLIT 8                   // grid (128, 8)
#define VRANGE (VOCAB / VSPLIT)    // 1024
#define NVT    (VRANGE / BV)       // 8
#define TAU 0.15f                  // rescue margin: >= 2*max|dist err| (fp16 inputs)

typedef _Float16 half8 __attribute__((ext_vector_type(8)));
typedef _Float16 half4 __attribute__((ext_vector_type(4)));
typedef float floatx4 __attribute__((ext_vector_type(4)));

// async global->LDS DMA, 16 B/lane; LDS dest = wave-uniform base + lane*16
__device__ __forceinline__ void load_lds16(const _Float16* g, _Float16* l) {
    __builtin_amdgcn_global_load_lds(
        (const __attribute__((address_space(1))) void*)g,
        (__attribute__((address_space(3))) void*)l, 16, 0, 0);
}

// ---------------------------------------------------------------------------
// PREP (1 dispatch replaces esq + split + memsets):
// blocks [0,2048): cb rows 4/block — fp16 convert + esq wave-reduce + zero
//                  cnt (4/block) + init rkey (8/block) + flagcnt (blk 0)
// blocks [2048,6144): z fp16 convert, 1 float4/thread
// ---------------------------------------------------------------------------
__global__ void prep_kernel(const float* __restrict__ z, const float* __restrict__ cb,
                            _Float16* __restrict__ zh, _Float16* __restrict__ ch,
                            float* __restrict__ esq, float* __restrict__ cnt,
                            unsigned long long* __restrict__ rkey,
                            int* __restrict__ flagcnt) {
    const int b = blockIdx.x, t = threadIdx.x;
    if (b < VOCAB / 4) {
        const int row  = b * 4 + (t >> 6);
        const int lane = t & 63;
        const float4 f = *(const float4*)(cb + (size_t)row * EMB + lane * 4);
        half4 h;
        h.x = (_Float16)f.x; h.y = (_Float16)f.y; h.z = (_Float16)f.z; h.w = (_Float16)f.w;
        *(half4*)(ch + (size_t)row * EMB + lane * 4) = h;
        float s = f.x * f.x + f.y * f.y + f.z * f.z + f.w * f.w;
        #pragma unroll
        for (int off = 32; off > 0; off >>= 1) s += __shfl_down(s, off, 64);
        if (lane == 0) esq[row] = s;
        if (t < 4) cnt[b * 4 + t] = 0.0f;
        if (t >= 8 && t < 16) rkey[b * 8 + (t - 8)] = ~0ull;
        if (b == 0 && t == 4) *flagcnt = 0;
    } else {
        const size_t idx4 = (size_t)(b - VOCAB / 4) * 256 + t;
        const float4 f = *(const float4*)(z + idx4 * 4);
        half4 h;
        h.x = (_Float16)f.x; h.y = (_Float16)f.y; h.z = (_Float16)f.z; h.w = (_Float16)f.w;
        *(half4*)(zh + idx4 * 4) = h;
    }
}

// ---------------------------------------------------------------------------
// MFMA dist kernel v8 (unchanged from round 8 so this round's counters
// finally score the XOR swizzle + BK=64 + esq-folded-init changes).
// acc init = -0.5*esq[col]  =>  dist = -2*acc; per-row ARGMAX of acc.
// LDS tiles [row][64 halfs] (128 B rows), XOR-swizzled chunks:
//   slot (r,c) holds global chunk (r, c ^ (r&7)).
// ---------------------------------------------------------------------------
__global__ __launch_bounds__(256, 3)
void mfma_dist_kernel(const _Float16* __restrict__ zh, const _Float16* __restrict__ ch,
                      const float* __restrict__ esq,
                      float* __restrict__ pd1, int* __restrict__ pi1,
                      float* __restrict__ pd2) {
    __shared__ _Float16 zs[BM * BK];   // 16 KB
    __shared__ _Float16 cs[BV * BK];   // 16 KB
    float* sc_d1 = (float*)zs;         // end-phase alias (3 KB)
    float* sc_d2 = sc_d1 + BM * 2;
    int*   sc_i1 = (int*)(sc_d2 + BM * 2);

    const int row0  = blockIdx.x * BM;
    const int vbase = blockIdx.y * VRANGE;

    const int tid  = threadIdx.x;
    const int w    = tid >> 6;
    const int lane = tid & 63;
    const int lr   = lane & 15;
    const int quad = lane >> 4;
    const int mh   = (w >> 1) * 64;    // wave m-origin
    const int vh   = (w & 1) * 64;     // wave v-origin

    // fragment read addressing (lane-constant, zero VALU in the hot loop)
    const int q7   = quad ^ (lr & 7);
    const int offA0 = q7 * 8;                // kstep 0 chunk offset (halfs)
    const int offA1 = (4 ^ q7) * 8;          // kstep 1
    int rA[4], rB[4];
    #pragma unroll
    for (int i = 0; i < 4; ++i) { rA[i] = (mh + i * 16 + lr) * BK; rB[i] = (vh + i * 16 + lr) * BK; }

    // staging addressing: slot ss = w*256 + q*64 + lane; r=ss>>3, c=lane&7
    const int schunk = (lane & 7) ^ (lane >> 3);            // c ^ (r&7), lane-const
    const _Float16* zsrc = zh + (size_t)(row0 + w * 32 + (lane >> 3)) * EMB + schunk * 8;

    // per-lane deferred top-2 (maximize acc): 16 rows per lane
    float m1[16], m2[16]; int i1[16];
    #pragma unroll
    for (int t = 0; t < 16; ++t) { m1[t] = -INFINITY; m2[t] = -INFINITY; i1[t] = 0; }

    // esq prefetch (vt=0)
    float ev[4];
    #pragma unroll
    for (int j = 0; j < 4; ++j) ev[j] = esq[vbase + vh + j * 16 + lr];

    for (int vt = 0; vt < NVT; ++vt) {
        const int v0 = vbase + vt * BV;
        const _Float16* csrc = ch + (size_t)(v0 + w * 32 + (lane >> 3)) * EMB + schunk * 8;

        // acc init = -0.5*esq[col]
        floatx4 acc[4][4];
        #pragma unroll
        for (int j = 0; j < 4; ++j) {
            const float e2 = -0.5f * ev[j];
            #pragma unroll
            for (int i = 0; i < 4; ++i) acc[i][j] = (floatx4)e2;
        }
        // prefetch next vt's esq (loads retire during kt loop)
        float evn[4];
        {
            const int vtn = (vt + 1 < NVT) ? vt + 1 : vt;
            #pragma unroll
            for (int j = 0; j < 4; ++j) evn[j] = esq[vbase + vtn * BV + vh + j * 16 + lr];
        }

        #pragma unroll 1
        for (int kt = 0; kt < EMB / BK; ++kt) {
            const int ko = kt * BK;
            #pragma unroll
            for (int q = 0; q < 4; ++q) {
                load_lds16(zsrc + (size_t)q * 8 * EMB + ko, &zs[w * 2048 + q * 512]);
                load_lds16(csrc + (size_t)q * 8 * EMB + ko, &cs[w * 2048 + q * 512]);
            }
            __syncthreads();

            #pragma unroll
            for (int s = 0; s < 2; ++s) {
                const int off = s ? offA1 : offA0;
                half8 a[4];
                #pragma unroll
                for (int i = 0; i < 4; ++i) a[i] = *(const half8*)&zs[rA[i] + off];
                #pragma unroll
                for (int j = 0; j < 4; ++j) {
                    const half8 b = *(const half8*)&cs[rB[j] + off];
                    #pragma unroll
                    for (int i = 0; i < 4; ++i)
                        acc[i][j] = __builtin_amdgcn_mfma_f32_16x16x32_f16(a[i], b, acc[i][j], 0, 0, 0);
                }
            }
            __syncthreads();
        }

        // epilogue: register-only top-2 (argmax acc)
        int vj[4];
        #pragma unroll
        for (int j = 0; j < 4; ++j) vj[j] = v0 + vh + j * 16 + lr;
        #pragma unroll
        for (int i = 0; i < 4; ++i) {
            #pragma unroll
            for (int reg = 0; reg < 4; ++reg) {
                const int t = i * 4 + reg;
                #pragma unroll
                for (int j = 0; j < 4; ++j) {
                    const float a = acc[i][j][reg];
                    m2[t] = fmaxf(m2[t], fminf(a, m1[t]));
                    i1[t] = (a > m1[t]) ? vj[j] : i1[t];
                    m1[t] = fmaxf(m1[t], a);
                }
            }
        }
        #pragma unroll
        for (int j = 0; j < 4; ++j) ev[j] = evn[j];
    }

    // ONE cross-lane reduce: 16 lr-lanes (same quad) share each row
    #pragma unroll
    for (int t = 0; t < 16; ++t) {
        float a1 = m1[t], a2 = m2[t]; int ii = i1[t];
        #pragma unroll
        for (int off = 1; off < 16; off <<= 1) {
            const float o1 = __shfl_xor(a1, off, 64);
            const int   oi = __shfl_xor(ii, off, 64);
            const float o2 = __shfl_xor(a2, off, 64);
            if (o1 > a1) { a2 = fmaxf(a1, o2); a1 = o1; ii = oi; }
            else         { a2 = fmaxf(a2, o1); }
        }
        m1[t] = a1; m2[t] = a2; i1[t] = ii;
    }
    if (lr == 0) {
        #pragma unroll
        for (int t = 0; t < 16; ++t) {
            const int r = mh + (t >> 2) * 16 + quad * 4 + (t & 3);
            sc_d1[r * 2 + (w & 1)] = m1[t];
            sc_d2[r * 2 + (w & 1)] = m2[t];
            sc_i1[r * 2 + (w & 1)] = i1[t];
        }
    }
    __syncthreads();
    if (tid < BM) {
        float a1 = sc_d1[tid * 2], a2 = sc_d2[tid * 2]; int ii = sc_i1[tid * 2];
        const float o1 = sc_d1[tid * 2 + 1], o2 = sc_d2[tid * 2 + 1];
        const int   oi = sc_i1[tid * 2 + 1];
        if (o1 > a1) { a2 = fmaxf(a1, o2); a1 = o1; ii = oi; }
        else         { a2 = fmaxf(a2, o1); }
        const size_t o = (size_t)blockIdx.y * N_ROWS + row0 + tid;
        pd1[o] = -2.0f * a1; pi1[o] = ii; pd2[o] = -2.0f * a2;
    }
}

// ---------------------------------------------------------------------------
// Combine: merge VSPLIT top-2 partials; margin >= TAU -> commit, else flag.
// ---------------------------------------------------------------------------
__global__ void combine_kernel(const float* __restrict__ pd1, const int* __restrict__ pi1,
                               const float* __restrict__ pd2,
                               const float* __restrict__ cb,
                               float* __restrict__ tokens, float* __restrict__ zq,
                               float* __restrict__ cnt,
                               int* __restrict__ flagcnt, int* __restrict__ flaglist) {
    const int wave = threadIdx.x >> 6;
    const int lane = threadIdx.x & 63;
    const int row  = blockIdx.x * 4 + wave;

    float d1 = INFINITY, d2 = INFINITY; int i1 = 0;
    #pragma unroll
    for (int s = 0; s < VSPLIT; ++s) {
        const size_t o = (size_t)s * N_ROWS + row;
        const float od1 = pd1[o], od2 = pd2[o]; const int oi1 = pi1[o];
        if (od1 < d1) { d2 = fminf(d1, od2); d1 = od1; i1 = oi1; }
        else          { d2 = fminf(d2, od1); }
    }
    if ((d2 - d1) < TAU) {
        if (lane == 0) {
            const int pos = atomicAdd(flagcnt, 1);
            flaglist[pos] = row;
        }
        return;   // rescue writes this row
    }
    if (lane == 0) {
        tokens[row] = (float)i1;
        atomicAdd(&cnt[i1], 1.0f);
    }
    const float4 v = *(const float4*)(cb + (size_t)i1 * EMB + lane * 4);
    *(float4*)(zq + (size_t)row * EMB + lane * 4) = v;
}

// ---------------------------------------------------------------------------
// Rescue v3 (round-7 form — NO fences, NO fused writer; round 8 proved the
// device-scope __threadfence per wave costs ~200 us in L2 writebacks).
// Job = (row, 32-code chunk) per wave; 4 lanes/code x 16 codes parallel.
// ---------------------------------------------------------------------------
__global__ void rescue3_kernel(const int* __restrict__ flagcnt, const int* __restrict__ flaglist,
                               const float* __restrict__ z, const float* __restrict__ cb,
                               const float* __restrict__ esq,
                               unsigned long long* __restrict__ rkey) {
    const int tid  = threadIdx.x;
    const int w    = tid >> 6;
    const int lane = tid & 63;
    const int g    = lane >> 2;
    const int s    = lane & 3;
    const int n = *flagcnt;
    const int waveId = blockIdx.x * 4 + w;
    const int nwaves = gridDim.x * 4;
    const int njobs  = n * 256;
    for (int j = waveId; j < njobs; j += nwaves) {
        const int row = flaglist[j >> 8];
        const int c0  = (j & 255) * 32;
        const float* zr = z + (size_t)row * EMB;
        float bd = INFINITY; int bv = 0;
        #pragma unroll
        for (int gs = 0; gs < 2; ++gs) {
            const int v = c0 + gs * 16 + g;
            const float* cr = cb + (size_t)v * EMB;
            float p = 0.0f;
            #pragma unroll
            for (int k = 0; k < 16; ++k) {
                const float4 c4 = *(const float4*)(cr + k * 16 + s * 4);
                const float4 z4 = *(const float4*)(zr + k * 16 + s * 4);
                p += z4.x * c4.x + z4.y * c4.y + z4.z * c4.z + z4.w * c4.w;
            }
            p += __shfl_xor(p, 1, 64);
            p += __shfl_xor(p, 2, 64);
            const float d = esq[v] - 2.0f * p;
            if (d < bd || (d == bd && v < bv)) { bd = d; bv = v; }
        }
        #pragma unroll
        for (int off = 4; off < 64; off <<= 1) {
            const float od = __shfl_xor(bd, off, 64);
            const int   ov = __shfl_xor(bv, off, 64);
            if (od < bd || (od == bd && ov < bv)) { bd = od; bv = ov; }
        }
        if (lane == 0) {
            unsigned int u = __float_as_uint(bd);
            u = (u & 0x80000000u) ? ~u : (u | 0x80000000u);
            atomicMin(rkey + row, ((unsigned long long)u << 32) | (unsigned int)bv);
        }
    }
}

// ---------------------------------------------------------------------------
// Rescue writer: separate dispatch (kernel boundary = visibility ordering).
// ---------------------------------------------------------------------------
__global__ void rescue_write_kernel(const int* __restrict__ flagcnt,
                                    const int* __restrict__ flaglist,
                                    const unsigned long long* __restrict__ rkey,
                                    const float* __restrict__ cb,
                                    float* __restrict__ tokens, float* __restrict__ zq,
                                    float* __restrict__ cnt) {
    const int w    = threadIdx.x >> 6;
    const int lane = threadIdx.x & 63;
    const int n = *flagcnt;
    for (int f = blockIdx.x * 4 + w; f < n; f += gridDim.x * 4) {
        const int row = flaglist[f];
        const int v = (int)(unsigned int)(rkey[row] & 0xFFFFFFFFull);
        if (lane == 0) {
            tokens[row] = (float)v;
            atomicAdd(&cnt[v], 1.0f);
        }
        const float4 c4 = *(const float4*)(cb + (size_t)v * EMB + lane * 4);
        *(float4*)(zq + (size_t)row * EMB + lane * 4) = c4;
    }
}

// ===========================================================================
// Fallback (round-3 fp32 path) if ws is too small.
// ===========================================================================
__global__ void esq_kernel(const float* __restrict__ cb, float* __restrict__ esq) {
    const int wave = threadIdx.x >> 6;
    const int lane = threadIdx.x & 63;
    const int row  = blockIdx.x * 4 + wave;
    const float4 v = *(const float4*)(cb + (size_t)row * EMB + lane * 4);
    float s = v.x * v.x + v.y * v.y + v.z * v.z + v.w * v.w;
    #pragma unroll
    for (int off = 32; off > 0; off >>= 1) s += __shfl_down(s, off, 64);
    if (lane == 0) esq[row] = s;
}

#define FLSTR 36
__global__ __launch_bounds__(256, 2)
void fb_dist_kernel(const float* __restrict__ z, const float* __restrict__ cb,
                    const float* __restrict__ esq,
                    float* __restrict__ pdist, int* __restrict__ pidx) {
    __shared__ float zs[BM][FLSTR];
    __shared__ float es[BV][FLSTR];
    __shared__ float rdist[16][16];
    __shared__ int   ridx [16][16];
    const int row0 = blockIdx.x * BM, vbase = blockIdx.y * VRANGE;
    const int tid = threadIdx.x, wave = tid >> 6, lane = tid & 63;
    const int wly = (lane >> 3) & 7, wlx = lane & 7;
    const int wbase = (wave >> 1) * 64, cbase = (wave & 1) * 64;
    const int arow = wbase + wly, bcol = cbase + wlx;
    const int rowSlot = (wave >> 1) * 8 + wly, colSlot = (wave & 1) * 8 + wlx;
    const int sc4 = tid & 7, sr0 = tid >> 3;
    float best[8]; int bidx[8];
    #pragma unroll
    for (int i = 0; i < 8; ++i) { best[i] = INFINITY; bidx[i] = 0; }
    for (int vt = 0; vt < NVT; ++vt) {
        const int v0 = vbase + vt * BV;
        float acc[8][8];
        #pragma unroll
        for (int i = 0; i < 8; ++i)
            #pragma unroll
            for (int j = 0; j < 8; ++j) acc[i][j] = 0.0f;
        #pragma unroll 1
        for (int kt = 0; kt < EMB / 32; ++kt) {
            #pragma unroll
            for (int t = 0; t < 4; ++t) {
                const int r = sr0 + 32 * t;
                *(float4*)&zs[r][sc4 * 4] = *(const float4*)(z  + (size_t)(row0 + r) * EMB + kt * 32 + sc4 * 4);
                *(float4*)&es[r][sc4 * 4] = *(const float4*)(cb + (size_t)(v0 + r) * EMB + kt * 32 + sc4 * 4);
            }
            __syncthreads();
            #pragma unroll 1
            for (int k0 = 0; k0 < 8; ++k0) {
                const int kk = k0 * 4;
                float a[8][4];
                #pragma unroll
                for (int i = 0; i < 8; ++i) {
                    const float4 a4 = *(const float4*)&zs[arow + 8 * i][kk];
                    a[i][0] = a4.x; a[i][1] = a4.y; a[i][2] = a4.z; a[i][3] = a4.w;
                }
                #pragma unroll
                for (int j = 0; j < 8; ++j) {
                    const float4 b4 = *(const float4*)&es[bcol + 8 * j][kk];
                    #pragma unroll
                    for (int i = 0; i < 8; ++i) {
                        acc[i][j] += a[i][0] * b4.x; acc[i][j] += a[i][1] * b4.y;
                        acc[i][j] += a[i][2] * b4.z; acc[i][j] += a[i][3] * b4.w;
                    }
                }
            }
            __syncthreads();
        }
        #pragma unroll
        for (int j = 0; j < 8; ++j) {
            const int v = v0 + bcol + 8 * j;
            const float evv = esq[v];
            #pragma unroll
            for (int i = 0; i < 8; ++i) {
                const float d = evv - 2.0f * acc[i][j];
                if (d < best[i]) { best[i] = d; bidx[i] = v; }
            }
        }
    }
    for (int i = 0; i < 8; ++i) {
        rdist[rowSlot][colSlot] = best[i];
        ridx [rowSlot][colSlot] = bidx[i];
        __syncthreads();
        if (colSlot == 0) {
            float bd = rdist[rowSlot][0]; int bi = ridx[rowSlot][0];
            #pragma unroll
            for (int t = 1; t < 16; ++t) {
                const float d = rdist[rowSlot][t]; const int ii = ridx[rowSlot][t];
                if (d < bd || (d == bd && ii < bi)) { bd = d; bi = ii; }
            }
            const int row = row0 + wbase + 8 * i + wly;
            pdist[(size_t)blockIdx.y * N_ROWS + row] = bd;
            pidx [(size_t)blockIdx.y * N_ROWS + row] = bi;
        }
        __syncthreads();
    }
}

__global__ void fb_combine_kernel(const float* __restrict__ pdist, const int* __restrict__ pidx,
                                  const float* __restrict__ cb,
                                  float* __restrict__ tokens, float* __restrict__ zq,
                                  float* __restrict__ cnt) {
    const int wave = threadIdx.x >> 6, lane = threadIdx.x & 63;
    const int row = blockIdx.x * 4 + wave;
    float bd = INFINITY; int bi = 0;
    #pragma unroll
    for (int s = 0; s < VSPLIT; ++s) {
        const float d = pdist[(size_t)s * N_ROWS + row];
        const int ii  = pidx [(size_t)s * N_ROWS + row];
        if (d < bd || (d == bd && ii < bi)) { bd = d; bi = ii; }
    }
    if (lane == 0) { tokens[row] = (float)bi; atomicAdd(&cnt[bi], 1.0f); }
    const float4 v = *(const float4*)(cb + (size_t)bi * EMB + lane * 4);
    *(float4*)(zq + (size_t)row * EMB + lane * 4) = v;
}

// ---------------------------------------------------------------------------
// d_out: [0,N) tokens | [N, N+N*EMB) zq | +VOCAB ref_count
// ws: zh | ch | esq | pd1|pd2|pi1 | rkey | flagcnt | flaglist  ~= 13.8 MB
// 5 dispatches: prep -> mfma_dist -> combine -> rescue3 -> rescue_write
// ---------------------------------------------------------------------------
extern "C" void kernel_launch(void* const* d_in, const int* in_sizes, int n_in,
                              void* d_out, int out_size, void* d_ws, size_t ws_size,
                              hipStream_t stream) {
    const float* z  = (const float*)d_in[0];
    const float* cb = (const float*)d_in[1];

    float* out    = (float*)d_out;
    float* tokens = out;
    float* zq     = out + N_ROWS;
    float* cnt    = out + N_ROWS + (size_t)N_ROWS * EMB;

    const size_t ZE = (size_t)N_ROWS * EMB, CE = (size_t)VOCAB * EMB, P = (size_t)VSPLIT * N_ROWS;
    const size_t NEED = (ZE + CE) * sizeof(_Float16) + VOCAB * 4
                      + 3 * P * 4 + (size_t)N_ROWS * 8 + 256 + N_ROWS * 4;

    if (ws_size >= NEED) {
        char* p = (char*)d_ws;
        _Float16* zh = (_Float16*)p;            p += ZE * 2;
        _Float16* ch = (_Float16*)p;            p += CE * 2;
        float* esq   = (float*)p;               p += VOCAB * 4;
        float* pd1   = (float*)p;               p += P * 4;
        float* pd2   = (float*)p;               p += P * 4;
        int*   pi1   = (int*)p;                 p += P * 4;
        unsigned long long* rkey = (unsigned long long*)p;  p += (size_t)N_ROWS * 8;
        int*   flagcnt = (int*)p;               p += 256;
        int*   flaglist = (int*)p;

        prep_kernel<<<VOCAB / 4 + (int)(ZE / 4 / 256), 256, 0, stream>>>(
            z, cb, zh, ch, esq, cnt, rkey, flagcnt);
        mfma_dist_kernel<<<dim3(N_ROWS / BM, VSPLIT), 256, 0, stream>>>(
            zh, ch, esq, pd1, pi1, pd2);
        combine_kernel<<<N_ROWS / 4, 256, 0, stream>>>(
            pd1, pi1, pd2, cb, tokens, zq, cnt, flagcnt, flaglist);
        rescue3_kernel<<<2048, 256, 0, stream>>>(flagcnt, flaglist, z, cb, esq, rkey);
        rescue_write_kernel<<<32, 256, 0, stream>>>(flagcnt, flaglist, rkey, cb, tokens, zq, cnt);
    } else {
        float* esq   = (float*)d_ws;
        float* pdist = esq + VOCAB;
        int*   pidx  = (int*)(pdist + P);
        hipMemsetAsync(cnt, 0, VOCAB * sizeof(float), stream);
        esq_kernel<<<VOCAB / 4, 256, 0, stream>>>(cb, esq);
        fb_dist_kernel<<<dim3(N_ROWS / BM, VSPLIT), 256, 0, stream>>>(z, cb, esq, pdist, pidx);
        fb_combine_kernel<<<N_ROWS / 4, 256, 0, stream>>>(pdist, pidx, cb, tokens, zq, cnt);
    }
}

// Round 10
// 279.735 us; speedup vs baseline: 1.7556x; 1.0639x over previous
//
#include <hip/hip_runtime.h>
#include <math.h>

#define N_ROWS 16384
#define VOCAB  8192
#define EMB    256

// ---- MFMA path tiling ----
#define BM 128
#define BV 128
#define BK 64                      // halfs per staged K-chunk (2 MFMA k-steps)
#define VSPLIT 8                   // grid (128, 8)
#define VRANGE (VOCAB / VSPLIT)    // 1024
#define NVT    (VRANGE / BV)       // 8
#define TAU 0.15f                  // rescue margin: >= 2*max|dist err| (fp16 inputs)

typedef _Float16 half8 __attribute__((ext_vector_type(8)));
typedef _Float16 half4 __attribute__((ext_vector_type(4)));
typedef float floatx4 __attribute__((ext_vector_type(4)));

// async global->LDS DMA, 16 B/lane; LDS dest = wave-uniform base + lane*16
__device__ __forceinline__ void load_lds16(const _Float16* g, _Float16* l) {
    __builtin_amdgcn_global_load_lds(
        (const __attribute__((address_space(1))) void*)g,
        (__attribute__((address_space(3))) void*)l, 16, 0, 0);
}

// ---------------------------------------------------------------------------
// PREP (1 dispatch replaces esq + split + memsets).
// ---------------------------------------------------------------------------
__global__ void prep_kernel(const float* __restrict__ z, const float* __restrict__ cb,
                            _Float16* __restrict__ zh, _Float16* __restrict__ ch,
                            float* __restrict__ esq, float* __restrict__ cnt,
                            unsigned long long* __restrict__ rkey,
                            int* __restrict__ flagcnt) {
    const int b = blockIdx.x, t = threadIdx.x;
    if (b < VOCAB / 4) {
        const int row  = b * 4 + (t >> 6);
        const int lane = t & 63;
        const float4 f = *(const float4*)(cb + (size_t)row * EMB + lane * 4);
        half4 h;
        h.x = (_Float16)f.x; h.y = (_Float16)f.y; h.z = (_Float16)f.z; h.w = (_Float16)f.w;
        *(half4*)(ch + (size_t)row * EMB + lane * 4) = h;
        float s = f.x * f.x + f.y * f.y + f.z * f.z + f.w * f.w;
        #pragma unroll
        for (int off = 32; off > 0; off >>= 1) s += __shfl_down(s, off, 64);
        if (lane == 0) esq[row] = s;
        if (t < 4) cnt[b * 4 + t] = 0.0f;
        if (t >= 8 && t < 16) rkey[b * 8 + (t - 8)] = ~0ull;
        if (b == 0 && t == 4) *flagcnt = 0;
    } else {
        const size_t idx4 = (size_t)(b - VOCAB / 4) * 256 + t;
        const float4 f = *(const float4*)(z + idx4 * 4);
        half4 h;
        h.x = (_Float16)f.x; h.y = (_Float16)f.y; h.z = (_Float16)f.z; h.w = (_Float16)f.w;
        *(half4*)(zh + idx4 * 4) = h;
    }
}

// ---------------------------------------------------------------------------
// MFMA dist kernel v8 (byte-identical to rounds 8/9 — isolate rescue change).
// acc init = -0.5*esq[col]  =>  dist = -2*acc; per-row ARGMAX of acc.
// LDS tiles [row][64 halfs], XOR-swizzled chunks (r,c)->(r, c^(r&7)).
// ---------------------------------------------------------------------------
__global__ __launch_bounds__(256, 3)
void mfma_dist_kernel(const _Float16* __restrict__ zh, const _Float16* __restrict__ ch,
                      const float* __restrict__ esq,
                      float* __restrict__ pd1, int* __restrict__ pi1,
                      float* __restrict__ pd2) {
    __shared__ _Float16 zs[BM * BK];   // 16 KB
    __shared__ _Float16 cs[BV * BK];   // 16 KB
    float* sc_d1 = (float*)zs;         // end-phase alias (3 KB)
    float* sc_d2 = sc_d1 + BM * 2;
    int*   sc_i1 = (int*)(sc_d2 + BM * 2);

    const int row0  = blockIdx.x * BM;
    const int vbase = blockIdx.y * VRANGE;

    const int tid  = threadIdx.x;
    const int w    = tid >> 6;
    const int lane = tid & 63;
    const int lr   = lane & 15;
    const int quad = lane >> 4;
    const int mh   = (w >> 1) * 64;
    const int vh   = (w & 1) * 64;

    const int q7   = quad ^ (lr & 7);
    const int offA0 = q7 * 8;
    const int offA1 = (4 ^ q7) * 8;
    int rA[4], rB[4];
    #pragma unroll
    for (int i = 0; i < 4; ++i) { rA[i] = (mh + i * 16 + lr) * BK; rB[i] = (vh + i * 16 + lr) * BK; }

    const int schunk = (lane & 7) ^ (lane >> 3);
    const _Float16* zsrc = zh + (size_t)(row0 + w * 32 + (lane >> 3)) * EMB + schunk * 8;

    float m1[16], m2[16]; int i1[16];
    #pragma unroll
    for (int t = 0; t < 16; ++t) { m1[t] = -INFINITY; m2[t] = -INFINITY; i1[t] = 0; }

    float ev[4];
    #pragma unroll
    for (int j = 0; j < 4; ++j) ev[j] = esq[vbase + vh + j * 16 + lr];

    for (int vt = 0; vt < NVT; ++vt) {
        const int v0 = vbase + vt * BV;
        const _Float16* csrc = ch + (size_t)(v0 + w * 32 + (lane >> 3)) * EMB + schunk * 8;

        floatx4 acc[4][4];
        #pragma unroll
        for (int j = 0; j < 4; ++j) {
            const float e2 = -0.5f * ev[j];
            #pragma unroll
            for (int i = 0; i < 4; ++i) acc[i][j] = (floatx4)e2;
        }
        float evn[4];
        {
            const int vtn = (vt + 1 < NVT) ? vt + 1 : vt;
            #pragma unroll
            for (int j = 0; j < 4; ++j) evn[j] = esq[vbase + vtn * BV + vh + j * 16 + lr];
        }

        #pragma unroll 1
        for (int kt = 0; kt < EMB / BK; ++kt) {
            const int ko = kt * BK;
            #pragma unroll
            for (int q = 0; q < 4; ++q) {
                load_lds16(zsrc + (size_t)q * 8 * EMB + ko, &zs[w * 2048 + q * 512]);
                load_lds16(csrc + (size_t)q * 8 * EMB + ko, &cs[w * 2048 + q * 512]);
            }
            __syncthreads();

            #pragma unroll
            for (int s = 0; s < 2; ++s) {
                const int off = s ? offA1 : offA0;
                half8 a[4];
                #pragma unroll
                for (int i = 0; i < 4; ++i) a[i] = *(const half8*)&zs[rA[i] + off];
                #pragma unroll
                for (int j = 0; j < 4; ++j) {
                    const half8 b = *(const half8*)&cs[rB[j] + off];
                    #pragma unroll
                    for (int i = 0; i < 4; ++i)
                        acc[i][j] = __builtin_amdgcn_mfma_f32_16x16x32_f16(a[i], b, acc[i][j], 0, 0, 0);
                }
            }
            __syncthreads();
        }

        int vj[4];
        #pragma unroll
        for (int j = 0; j < 4; ++j) vj[j] = v0 + vh + j * 16 + lr;
        #pragma unroll
        for (int i = 0; i < 4; ++i) {
            #pragma unroll
            for (int reg = 0; reg < 4; ++reg) {
                const int t = i * 4 + reg;
                #pragma unroll
                for (int j = 0; j < 4; ++j) {
                    const float a = acc[i][j][reg];
                    m2[t] = fmaxf(m2[t], fminf(a, m1[t]));
                    i1[t] = (a > m1[t]) ? vj[j] : i1[t];
                    m1[t] = fmaxf(m1[t], a);
                }
            }
        }
        #pragma unroll
        for (int j = 0; j < 4; ++j) ev[j] = evn[j];
    }

    #pragma unroll
    for (int t = 0; t < 16; ++t) {
        float a1 = m1[t], a2 = m2[t]; int ii = i1[t];
        #pragma unroll
        for (int off = 1; off < 16; off <<= 1) {
            const float o1 = __shfl_xor(a1, off, 64);
            const int   oi = __shfl_xor(ii, off, 64);
            const float o2 = __shfl_xor(a2, off, 64);
            if (o1 > a1) { a2 = fmaxf(a1, o2); a1 = o1; ii = oi; }
            else         { a2 = fmaxf(a2, o1); }
        }
        m1[t] = a1; m2[t] = a2; i1[t] = ii;
    }
    if (lr == 0) {
        #pragma unroll
        for (int t = 0; t < 16; ++t) {
            const int r = mh + (t >> 2) * 16 + quad * 4 + (t & 3);
            sc_d1[r * 2 + (w & 1)] = m1[t];
            sc_d2[r * 2 + (w & 1)] = m2[t];
            sc_i1[r * 2 + (w & 1)] = i1[t];
        }
    }
    __syncthreads();
    if (tid < BM) {
        float a1 = sc_d1[tid * 2], a2 = sc_d2[tid * 2]; int ii = sc_i1[tid * 2];
        const float o1 = sc_d1[tid * 2 + 1], o2 = sc_d2[tid * 2 + 1];
        const int   oi = sc_i1[tid * 2 + 1];
        if (o1 > a1) { a2 = fmaxf(a1, o2); a1 = o1; ii = oi; }
        else         { a2 = fmaxf(a2, o1); }
        const size_t o = (size_t)blockIdx.y * N_ROWS + row0 + tid;
        pd1[o] = -2.0f * a1; pi1[o] = ii; pd2[o] = -2.0f * a2;
    }
}

// ---------------------------------------------------------------------------
// Combine: merge VSPLIT top-2 partials; margin >= TAU -> commit, else flag.
// ---------------------------------------------------------------------------
__global__ void combine_kernel(const float* __restrict__ pd1, const int* __restrict__ pi1,
                               const float* __restrict__ pd2,
                               const float* __restrict__ cb,
                               float* __restrict__ tokens, float* __restrict__ zq,
                               float* __restrict__ cnt,
                               int* __restrict__ flagcnt, int* __restrict__ flaglist) {
    const int wave = threadIdx.x >> 6;
    const int lane = threadIdx.x & 63;
    const int row  = blockIdx.x * 4 + wave;

    float d1 = INFINITY, d2 = INFINITY; int i1 = 0;
    #pragma unroll
    for (int s = 0; s < VSPLIT; ++s) {
        const size_t o = (size_t)s * N_ROWS + row;
        const float od1 = pd1[o], od2 = pd2[o]; const int oi1 = pi1[o];
        if (od1 < d1) { d2 = fminf(d1, od2); d1 = od1; i1 = oi1; }
        else          { d2 = fminf(d2, od1); }
    }
    if ((d2 - d1) < TAU) {
        if (lane == 0) {
            const int pos = atomicAdd(flagcnt, 1);
            flaglist[pos] = row;
        }
        return;   // rescue writes this row
    }
    if (lane == 0) {
        tokens[row] = (float)i1;
        atomicAdd(&cnt[i1], 1.0f);
    }
    const float4 v = *(const float4*)(cb + (size_t)i1 * EMB + lane * 4);
    *(float4*)(zq + (size_t)row * EMB + lane * 4) = v;
}

// ---------------------------------------------------------------------------
// Rescue v4: exact fp32 argmin, ILP-restructured (round 9 showed v3 is
// L2-latency bound: 1 serial dot chain/lane, VALUBusy 24%).
// Job = (row, 64-code chunk) per wave; 4 lanes/code x 16 codes; FOUR
// independent accumulator chains per lane (one per 16-code group-step)
// sharing z fragments loaded once per k-block -> ~20 loads in flight.
// ---------------------------------------------------------------------------
__global__ void rescue4_kernel(const int* __restrict__ flagcnt, const int* __restrict__ flaglist,
                               const float* __restrict__ z, const float* __restrict__ cb,
                               const float* __restrict__ esq,
                               unsigned long long* __restrict__ rkey) {
    const int tid  = threadIdx.x;
    const int w    = tid >> 6;
    const int lane = tid & 63;
    const int g    = lane >> 2;        // code group 0..15
    const int s    = lane & 3;         // sub-lane: dims k*16 + s*4
    const int n = *flagcnt;
    const int waveId = blockIdx.x * 4 + w;
    const int nwaves = gridDim.x * 4;
    const int njobs  = n * 128;        // 128 chunks of 64 codes per row
    for (int j = waveId; j < njobs; j += nwaves) {
        const int row = flaglist[j >> 7];
        const int c0  = (j & 127) * 64;
        const float* zr = z + (size_t)row * EMB;
        float p[4] = {0.0f, 0.0f, 0.0f, 0.0f};
        #pragma unroll
        for (int kb = 0; kb < 4; ++kb) {
            float4 zv[4];
            #pragma unroll
            for (int kk = 0; kk < 4; ++kk)
                zv[kk] = *(const float4*)(zr + (kb * 4 + kk) * 16 + s * 4);
            #pragma unroll
            for (int gs = 0; gs < 4; ++gs) {
                const float* cr = cb + (size_t)(c0 + gs * 16 + g) * EMB;
                #pragma unroll
                for (int kk = 0; kk < 4; ++kk) {
                    const float4 c4 = *(const float4*)(cr + (kb * 4 + kk) * 16 + s * 4);
                    p[gs] += zv[kk].x * c4.x + zv[kk].y * c4.y
                           + zv[kk].z * c4.z + zv[kk].w * c4.w;
                }
            }
        }
        float bd = INFINITY; int bv = 0;
        #pragma unroll
        for (int gs = 0; gs < 4; ++gs) {
            float pp = p[gs];
            pp += __shfl_xor(pp, 1, 64);
            pp += __shfl_xor(pp, 2, 64);     // all 4 quad lanes hold full dot
            const int v = c0 + gs * 16 + g;
            const float d = esq[v] - 2.0f * pp;
            if (d < bd) { bd = d; bv = v; }  // gs ascending -> lowest tie index
        }
        #pragma unroll
        for (int off = 4; off < 64; off <<= 1) {
            const float od = __shfl_xor(bd, off, 64);
            const int   ov = __shfl_xor(bv, off, 64);
            if (od < bd || (od == bd && ov < bv)) { bd = od; bv = ov; }
        }
        if (lane == 0) {
            unsigned int u = __float_as_uint(bd);
            u = (u & 0x80000000u) ? ~u : (u | 0x80000000u);
            atomicMin(rkey + row, ((unsigned long long)u << 32) | (unsigned int)bv);
        }
    }
}

// ---------------------------------------------------------------------------
// Rescue writer: separate dispatch (kernel boundary = visibility ordering).
// ---------------------------------------------------------------------------
__global__ void rescue_write_kernel(const int* __restrict__ flagcnt,
                                    const int* __restrict__ flaglist,
                                    const unsigned long long* __restrict__ rkey,
                                    const float* __restrict__ cb,
                                    float* __restrict__ tokens, float* __restrict__ zq,
                                    float* __restrict__ cnt) {
    const int w    = threadIdx.x >> 6;
    const int lane = threadIdx.x & 63;
    const int n = *flagcnt;
    for (int f = blockIdx.x * 4 + w; f < n; f += gridDim.x * 4) {
        const int row = flaglist[f];
        const int v = (int)(unsigned int)(rkey[row] & 0xFFFFFFFFull);
        if (lane == 0) {
            tokens[row] = (float)v;
            atomicAdd(&cnt[v], 1.0f);
        }
        const float4 c4 = *(const float4*)(cb + (size_t)v * EMB + lane * 4);
        *(float4*)(zq + (size_t)row * EMB + lane * 4) = c4;
    }
}

// ===========================================================================
// Fallback (round-3 fp32 path) if ws is too small.
// ===========================================================================
__global__ void esq_kernel(const float* __restrict__ cb, float* __restrict__ esq) {
    const int wave = threadIdx.x >> 6;
    const int lane = threadIdx.x & 63;
    const int row  = blockIdx.x * 4 + wave;
    const float4 v = *(const float4*)(cb + (size_t)row * EMB + lane * 4);
    float s = v.x * v.x + v.y * v.y + v.z * v.z + v.w * v.w;
    #pragma unroll
    for (int off = 32; off > 0; off >>= 1) s += __shfl_down(s, off, 64);
    if (lane == 0) esq[row] = s;
}

#define FLSTR 36
__global__ __launch_bounds__(256, 2)
void fb_dist_kernel(const float* __restrict__ z, const float* __restrict__ cb,
                    const float* __restrict__ esq,
                    float* __restrict__ pdist, int* __restrict__ pidx) {
    __shared__ float zs[BM][FLSTR];
    __shared__ float es[BV][FLSTR];
    __shared__ float rdist[16][16];
    __shared__ int   ridx [16][16];
    const int row0 = blockIdx.x * BM, vbase = blockIdx.y * VRANGE;
    const int tid = threadIdx.x, wave = tid >> 6, lane = tid & 63;
    const int wly = (lane >> 3) & 7, wlx = lane & 7;
    const int wbase = (wave >> 1) * 64, cbase = (wave & 1) * 64;
    const int arow = wbase + wly, bcol = cbase + wlx;
    const int rowSlot = (wave >> 1) * 8 + wly, colSlot = (wave & 1) * 8 + wlx;
    const int sc4 = tid & 7, sr0 = tid >> 3;
    float best[8]; int bidx[8];
    #pragma unroll
    for (int i = 0; i < 8; ++i) { best[i] = INFINITY; bidx[i] = 0; }
    for (int vt = 0; vt < NVT; ++vt) {
        const int v0 = vbase + vt * BV;
        float acc[8][8];
        #pragma unroll
        for (int i = 0; i < 8; ++i)
            #pragma unroll
            for (int j = 0; j < 8; ++j) acc[i][j] = 0.0f;
        #pragma unroll 1
        for (int kt = 0; kt < EMB / 32; ++kt) {
            #pragma unroll
            for (int t = 0; t < 4; ++t) {
                const int r = sr0 + 32 * t;
                *(float4*)&zs[r][sc4 * 4] = *(const float4*)(z  + (size_t)(row0 + r) * EMB + kt * 32 + sc4 * 4);
                *(float4*)&es[r][sc4 * 4] = *(const float4*)(cb + (size_t)(v0 + r) * EMB + kt * 32 + sc4 * 4);
            }
            __syncthreads();
            #pragma unroll 1
            for (int k0 = 0; k0 < 8; ++k0) {
                const int kk = k0 * 4;
                float a[8][4];
                #pragma unroll
                for (int i = 0; i < 8; ++i) {
                    const float4 a4 = *(const float4*)&zs[arow + 8 * i][kk];
                    a[i][0] = a4.x; a[i][1] = a4.y; a[i][2] = a4.z; a[i][3] = a4.w;
                }
                #pragma unroll
                for (int j = 0; j < 8; ++j) {
                    const float4 b4 = *(const float4*)&es[bcol + 8 * j][kk];
                    #pragma unroll
                    for (int i = 0; i < 8; ++i) {
                        acc[i][j] += a[i][0] * b4.x; acc[i][j] += a[i][1] * b4.y;
                        acc[i][j] += a[i][2] * b4.z; acc[i][j] += a[i][3] * b4.w;
                    }
                }
            }
            __syncthreads();
        }
        #pragma unroll
        for (int j = 0; j < 8; ++j) {
            const int v = v0 + bcol + 8 * j;
            const float evv = esq[v];
            #pragma unroll
            for (int i = 0; i < 8; ++i) {
                const float d = evv - 2.0f * acc[i][j];
                if (d < best[i]) { best[i] = d; bidx[i] = v; }
            }
        }
    }
    for (int i = 0; i < 8; ++i) {
        rdist[rowSlot][colSlot] = best[i];
        ridx [rowSlot][colSlot] = bidx[i];
        __syncthreads();
        if (colSlot == 0) {
            float bd = rdist[rowSlot][0]; int bi = ridx[rowSlot][0];
            #pragma unroll
            for (int t = 1; t < 16; ++t) {
                const float d = rdist[rowSlot][t]; const int ii = ridx[rowSlot][t];
                if (d < bd || (d == bd && ii < bi)) { bd = d; bi = ii; }
            }
            const int row = row0 + wbase + 8 * i + wly;
            pdist[(size_t)blockIdx.y * N_ROWS + row] = bd;
            pidx [(size_t)blockIdx.y * N_ROWS + row] = bi;
        }
        __syncthreads();
    }
}

__global__ void fb_combine_kernel(const float* __restrict__ pdist, const int* __restrict__ pidx,
                                  const float* __restrict__ cb,
                                  float* __restrict__ tokens, float* __restrict__ zq,
                                  float* __restrict__ cnt) {
    const int wave = threadIdx.x >> 6, lane = threadIdx.x & 63;
    const int row = blockIdx.x * 4 + wave;
    float bd = INFINITY; int bi = 0;
    #pragma unroll
    for (int s = 0; s < VSPLIT; ++s) {
        const float d = pdist[(size_t)s * N_ROWS + row];
        const int ii  = pidx [(size_t)s * N_ROWS + row];
        if (d < bd || (d == bd && ii < bi)) { bd = d; bi = ii; }
    }
    if (lane == 0) { tokens[row] = (float)bi; atomicAdd(&cnt[bi], 1.0f); }
    const float4 v = *(const float4*)(cb + (size_t)bi * EMB + lane * 4);
    *(float4*)(zq + (size_t)row * EMB + lane * 4) = v;
}

// ---------------------------------------------------------------------------
// d_out: [0,N) tokens | [N, N+N*EMB) zq | +VOCAB ref_count
// ws: zh | ch | esq | pd1|pd2|pi1 | rkey | flagcnt | flaglist  ~= 13.8 MB
// 5 dispatches: prep -> mfma_dist -> combine -> rescue4 -> rescue_write
// ---------------------------------------------------------------------------
extern "C" void kernel_launch(void* const* d_in, const int* in_sizes, int n_in,
                              void* d_out, int out_size, void* d_ws, size_t ws_size,
                              hipStream_t stream) {
    const float* z  = (const float*)d_in[0];
    const float* cb = (const float*)d_in[1];

    float* out    = (float*)d_out;
    float* tokens = out;
    float* zq     = out + N_ROWS;
    float* cnt    = out + N_ROWS + (size_t)N_ROWS * EMB;

    const size_t ZE = (size_t)N_ROWS * EMB, CE = (size_t)VOCAB * EMB, P = (size_t)VSPLIT * N_ROWS;
    const size_t NEED = (ZE + CE) * sizeof(_Float16) + VOCAB * 4
                      + 3 * P * 4 + (size_t)N_ROWS * 8 + 256 + N_ROWS * 4;

    if (ws_size >= NEED) {
        char* p = (char*)d_ws;
        _Float16* zh = (_Float16*)p;            p += ZE * 2;
        _Float16* ch = (_Float16*)p;            p += CE * 2;
        float* esq   = (float*)p;               p += VOCAB * 4;
        float* pd1   = (float*)p;               p += P * 4;
        float* pd2   = (float*)p;               p += P * 4;
        int*   pi1   = (int*)p;                 p += P * 4;
        unsigned long long* rkey = (unsigned long long*)p;  p += (size_t)N_ROWS * 8;
        int*   flagcnt = (int*)p;               p += 256;
        int*   flaglist = (int*)p;

        prep_kernel<<<VOCAB / 4 + (int)(ZE / 4 / 256), 256, 0, stream>>>(
            z, cb, zh, ch, esq, cnt, rkey, flagcnt);
        mfma_dist_kernel<<<dim3(N_ROWS / BM, VSPLIT), 256, 0, stream>>>(
            zh, ch, esq, pd1, pi1, pd2);
        combine_kernel<<<N_ROWS / 4, 256, 0, stream>>>(
            pd1, pi1, pd2, cb, tokens, zq, cnt, flagcnt, flaglist);
        rescue4_kernel<<<2048, 256, 0, stream>>>(flagcnt, flaglist, z, cb, esq, rkey);
        rescue_write_kernel<<<32, 256, 0, stream>>>(flagcnt, flaglist, rkey, cb, tokens, zq, cnt);
    } else {
        float* esq   = (float*)d_ws;
        float* pdist = esq + VOCAB;
        int*   pidx  = (int*)(pdist + P);
        hipMemsetAsync(cnt, 0, VOCAB * sizeof(float), stream);
        esq_kernel<<<VOCAB / 4, 256, 0, stream>>>(cb, esq);
        fb_dist_kernel<<<dim3(N_ROWS / BM, VSPLIT), 256, 0, stream>>>(z, cb, esq, pdist, pidx);
        fb_combine_kernel<<<N_ROWS / 4, 256, 0, stream>>>(pdist, pidx, cb, tokens, zq, cnt);
    }
}